// Round 6
// baseline (17.632 us; speedup 1.0000x reference)
//
#include <hip/hip_runtime.h>
#include <hip/hip_fp16.h>
#include <stdint.h>

// out[8,8192] = x[8,8192] @ W.T, W[n,k] = nibble(Qidxs[n,k/8], INV[k%8]) - 7.5
// Kernel 1 (build_atable): precompute the shared MFMA A-frag table in d_ws:
//   [512 K-steps][17 slots][16B] (slot 16 = zeros for padding rows), pitch 272B.
// Kernel 2 (hi4b_gemm): 256 blocks x 1024 threads (16 waves). Block owns 32 n-rows,
//   wave owns 512 K (2 subchunks of 256 K). B: coalesced global->reg->LDS (wave-
//   private, no barriers). A: global->VGPR direct from table, 8-step tiles, 2 in
//   flight. End: one barrier + 16-way LDS reduce + coalesced store.

typedef _Float16 half8 __attribute__((ext_vector_type(8)));
typedef float floatx16 __attribute__((ext_vector_type(16)));

union H2U { unsigned u; __half2 h; };
union V4H8 { uint4 u4; half8 h8; };

// (1024+n) exact -> -1024 -> -7.5  (all exact in f16)
__device__ __forceinline__ unsigned unpack_even(unsigned ws, __half2 c1, __half2 c2) {
    H2U t; t.u = (ws & 0x000F000Fu) | 0x64006400u;
    t.h = __hadd2(__hadd2(t.h, c1), c2);
    return t.u;
}
// (1024+16n) exact -> *1/16 - 71.5 = n - 7.5 (exact fma)
__device__ __forceinline__ unsigned unpack_odd(unsigned ws, __half2 cs, __half2 cc) {
    H2U t; t.u = (ws & 0x00F000F0u) | 0x64006400u;
    t.h = __hfma2(t.h, cs, cc);
    return t.u;
}

#define BPITCH 136                 // 32 words + 8B pad (conflict-light ds_read_b64)
#define BBUF   (32 * BPITCH)       // 4352 B: B buffer (32 rows x 32 words)
#define NW     16
#define LDS_BYTES (NW * BBUF)      // 69632 (reduce area aliased at offset 0)
#define TPITCH 272                 // A-table step pitch: 17 slots x 16B

__global__ void build_atable(const float* __restrict__ x, char* __restrict__ tbl)
{
    const int gid  = blockIdx.x * 256 + threadIdx.x;   // 0..8191
    const int S    = gid >> 4, slot = gid & 15;
    const int uu   = slot >> 3, rr = slot & 7;
    const float4* x4 = (const float4*)x;               // 2048 float4 per b-row
    float4 fa = x4[rr * 2048 + 4 * S + uu];            // cols 16S+4uu .. +3
    float4 fb = x4[rr * 2048 + 4 * S + 2 + uu];        // cols 16S+8+4uu .. +3
    H2U a0, a1, a2, a3;
    a0.h = __floats2half2_rn(fa.x, fa.y);
    a1.h = __floats2half2_rn(fa.z, fa.w);
    a2.h = __floats2half2_rn(fb.x, fb.y);
    a3.h = __floats2half2_rn(fb.z, fb.w);
    *(uint4*)(tbl + S * TPITCH + slot * 16) = make_uint4(a0.u, a1.u, a2.u, a3.u);
    if (slot == 0)                                     // zero slot (padding rows 8..31)
        *(uint4*)(tbl + S * TPITCH + 256) = make_uint4(0u, 0u, 0u, 0u);
}

__global__ __launch_bounds__(1024, 4)
void hi4b_gemm(const char* __restrict__ atbl, const int* __restrict__ q,
               float* __restrict__ out)
{
    extern __shared__ char lds[];
    const int tid  = threadIdx.x;
    const int lane = tid & 63;
    const int wv   = tid >> 6;            // 0..15: K-window wv*512
    const int n0   = blockIdx.x * 32;

    const int nlo = lane & 31;
    const int u   = lane >> 5;
    const int sh  = 8 * u;
    const int c   = lane & 7;             // uint4 within row-subchunk
    const int r0  = lane >> 3;            // 0..7

    const uint4* q4 = (const uint4*)q;    // 256 uint4 per n-row
    const int qbase = (n0 + r0) * 256 + wv * 16 + c;

    char* Bw = lds + wv * BBUF;

    // A: direct global reads from the precomputed frag table
    const int aslot = (nlo < 8) ? (u * 8 + nlo) : 16;
    const char* ab = atbl + (wv * 32) * TPITCH + aslot * 16;

    uint4 rb0, rb1, rb2, rb3;
    auto loadB = [&](int sc) {
        int b = qbase + sc * 8;                 // subchunk = 8 uint4 per row
        rb0 = q4[b];
        rb1 = q4[b +  8 * 256];
        rb2 = q4[b + 16 * 256];
        rb3 = q4[b + 24 * 256];
    };
    auto writeB = [&]() {
        char* p0 = Bw + (r0     ) * BPITCH + c * 16;
        char* p1 = Bw + (r0 +  8) * BPITCH + c * 16;
        char* p2 = Bw + (r0 + 16) * BPITCH + c * 16;
        char* p3 = Bw + (r0 + 24) * BPITCH + c * 16;
        *(uint2*)(p0)     = make_uint2(rb0.x, rb0.y);
        *(uint2*)(p0 + 8) = make_uint2(rb0.z, rb0.w);
        *(uint2*)(p1)     = make_uint2(rb1.x, rb1.y);
        *(uint2*)(p1 + 8) = make_uint2(rb1.z, rb1.w);
        *(uint2*)(p2)     = make_uint2(rb2.x, rb2.y);
        *(uint2*)(p2 + 8) = make_uint2(rb2.z, rb2.w);
        *(uint2*)(p3)     = make_uint2(rb3.x, rb3.y);
        *(uint2*)(p3 + 8) = make_uint2(rb3.z, rb3.w);
    };

    uint4 TA[8], TB[8];
    auto loadA = [&](uint4 (&T)[8], int tile) {     // tile = 8 steps
        const char* p = ab + tile * (8 * TPITCH);
        #pragma unroll
        for (int i = 0; i < 8; ++i)
            T[i] = *(const uint4*)(p + i * TPITCH);  // imm offsets 0..1904
    };

    const __half2 c1 = __floats2half2_rn(-1024.0f, -1024.0f);
    const __half2 c2 = __floats2half2_rn(-7.5f, -7.5f);
    const __half2 cs = __floats2half2_rn(0.0625f, 0.0625f);
    const __half2 cc = __floats2half2_rn(-71.5f, -71.5f);

    floatx16 acc;
    #pragma unroll
    for (int i = 0; i < 16; ++i) acc[i] = 0.0f;

    const char* bp = Bw + nlo * BPITCH;

    auto compute8 = [&](uint4 (&T)[8], int s0) {
        #pragma unroll
        for (int i = 0; i < 8; ++i) {
            uint2 w2 = *(const uint2*)(bp + (s0 + i) * 8);
            V4H8 A;  A.u4 = T[i];
            unsigned wsa = w2.x >> sh;
            unsigned wsb = w2.y >> sh;
            V4H8 Bf;
            Bf.u4.x = unpack_even(wsa, c1, c2);
            Bf.u4.y = unpack_odd (wsa, cs, cc);
            Bf.u4.z = unpack_even(wsb, c1, c2);
            Bf.u4.w = unpack_odd (wsb, cs, cc);
            acc = __builtin_amdgcn_mfma_f32_32x32x16_f16(A.h8, Bf.h8, acc, 0, 0, 0);
        }
    };

    // ---- pipeline: B single-buffered LDS (in-order DS => safe), A 2 reg-tiles ----
    loadB(0);
    loadA(TA, 0);
    loadA(TB, 1);
    writeB();              // stage sc0
    loadB(1);              // prefetch sc1
    compute8(TA, 0);       // sc0 steps 0..7
    loadA(TA, 2);
    compute8(TB, 8);       // sc0 steps 8..15
    writeB();              // stage sc1 (after sc0 reads; DS in-order)
    loadA(TB, 3);
    compute8(TA, 0);       // sc1 steps 0..7
    compute8(TB, 8);       // sc1 steps 8..15

    // ---- cross-wave reduce: 16 tiles of 8 b-rows x 32 n-cols, aliased over LDS ----
    __syncthreads();
    {
        float* red = (float*)lds + wv * 256;
        #pragma unroll
        for (int r = 0; r < 4; ++r)
            red[(r + 4 * u) * 32 + nlo] = acc[r];
    }
    __syncthreads();
    if (tid < 256) {
        const int b = tid >> 5, nl = tid & 31;
        const float* rd = (const float*)lds;
        float sm = 0.0f;
        #pragma unroll
        for (int w = 0; w < NW; ++w)
            sm += rd[w * 256 + b * 32 + nl];
        out[b * 8192 + n0 + nl] = sm;
    }
}

extern "C" void kernel_launch(void* const* d_in, const int* in_sizes, int n_in,
                              void* d_out, int out_size, void* d_ws, size_t ws_size,
                              hipStream_t stream)
{
    const float* x = (const float*)d_in[0];
    const int*   q = (const int*)d_in[1];
    float* out = (float*)d_out;
    char*  tbl = (char*)d_ws;              // 512*272 = 139264 B

    hipLaunchKernelGGL(build_atable, dim3(32), dim3(256), 0, stream, x, tbl);
    hipLaunchKernelGGL(hi4b_gemm, dim3(256), dim3(1024), LDS_BYTES, stream,
                       tbl, q, out);
}

// Round 7
// 17.052 us; speedup vs baseline: 1.0340x; 1.0340x over previous
//
#include <hip/hip_runtime.h>
#include <hip/hip_fp16.h>
#include <stdint.h>

// out[8,8192] = x[8,8192] @ W.T, W[n,k] = nibble(Qidxs[n,k/8], INV[k%8]) - 7.5
// Shape change: mfma_f32_16x16x32_f16. One Q-word (8 nibbles) = one lane's full
// B-frag for one MFMA step -> 1 ds_read_b32 + 13 VALU per MFMA.
// Kernel 1: A-frag table [256 steps][33 slots][16B] (slot 32 = zeros) in d_ws.
// Kernel 2: 512 blocks (16 n-rows each) x 512 threads (8 waves; wave owns 1024 K).
//   B: one-shot coalesced global->LDS stage per wave (private, no barriers).
//   A: global->VGPR from table, 4-step tiles, 2 in flight.
//   End: one barrier + 8-way LDS reduce + coalesced store.

typedef _Float16 half8 __attribute__((ext_vector_type(8)));
typedef float floatx4 __attribute__((ext_vector_type(4)));

union H2U { unsigned u; __half2 h; };
union V4H8 { uint4 u4; half8 h8; };

// nibbles {b, b+4} of w -> f16 pair {n_b, n_{b+4}} - 7.5, exact
__device__ __forceinline__ unsigned unpack_even(unsigned w, __half2 c1, __half2 c2) {
    H2U t; t.u = (w & 0x000F000Fu) | 0x64006400u;      // 1024 + n
    t.h = __hadd2(__hadd2(t.h, c1), c2);               // -1024, -7.5
    return t.u;
}
__device__ __forceinline__ unsigned unpack_odd(unsigned w, __half2 cs, __half2 cc) {
    H2U t; t.u = (w & 0x00F000F0u) | 0x64006400u;      // 1024 + 16n
    t.h = __hfma2(t.h, cs, cc);                        // /16, -71.5
    return t.u;
}

#define TPITCH 528                  // 33 slots x 16B per step
#define TBYTES (256 * TPITCH)       // 135168
#define BP     528                  // B row pitch: 132 words (128 + 4 pad)
#define BWAVE  (16 * BP)            // 8448 B per wave (16 rows x 128 words)
#define NWV    8
#define REDOFF (NWV * BWAVE)        // 67584
#define LDS_BYTES (REDOFF + NWV * 128 * 4)   // 71680 (x2 blocks/CU = 143 KB)

// ---- kernel 1: one block per K-step (256 x 64 threads) ----
__global__ void build_atable(const float* __restrict__ x, char* __restrict__ tbl)
{
    const int S = blockIdx.x;           // 0..255, k-base = 32*S
    const int t = threadIdx.x;          // 0..63; 0..32 active
    if (t > 32) return;
    uint4 v = make_uint4(0u, 0u, 0u, 0u);
    if (t < 32) {
        const int u = t >> 3, r = t & 7;            // slot = 8u + r
        const float4* x4 = (const float4*)x;        // 2048 float4 per b-row
        float4 fa = x4[r * 2048 + 8 * S + 2 * u];       // cols 32S+8u+0..3
        float4 fb = x4[r * 2048 + 8 * S + 2 * u + 1];   // cols 32S+8u+4..7
        H2U a0, a1, a2, a3;
        a0.h = __floats2half2_rn(fa.x, fa.y);
        a1.h = __floats2half2_rn(fa.z, fa.w);
        a2.h = __floats2half2_rn(fb.x, fb.y);
        a3.h = __floats2half2_rn(fb.z, fb.w);
        v = make_uint4(a0.u, a1.u, a2.u, a3.u);
    }
    // slot index: t<32 -> u*8+r ; t==32 -> zero slot
    const int slot = (t < 32) ? ((t >> 3) * 8 + (t & 7)) : 32;
    *(uint4*)(tbl + S * TPITCH + slot * 16) = v;
}

__global__ __launch_bounds__(512, 4)
void hi4b_gemm(const char* __restrict__ atbl, const int* __restrict__ q,
               float* __restrict__ out)
{
    extern __shared__ char lds[];
    const int tid  = threadIdx.x;
    const int lane = tid & 63;
    const int wv   = tid >> 6;            // 0..7: K-window wv*1024
    const int n0   = blockIdx.x * 16;

    const int r16 = lane & 15;            // n (B) / m (A) / C col
    const int u4  = lane >> 4;            // kgroup

    // ---- stage B once: 16 rows x 128 words, coalesced 64B/row segments ----
    {
        const int r0 = lane >> 2, ci = lane & 3;
        const uint4* q4 = (const uint4*)q;            // 256 uint4 per n-row
        const int gb = (n0 + r0) * 256 + wv * 32 + ci;
        char* Bw = lds + wv * BWAVE + r0 * BP + ci * 16;
        uint4 v[8];
        #pragma unroll
        for (int i = 0; i < 8; ++i) v[i] = q4[gb + 4 * i];
        #pragma unroll
        for (int i = 0; i < 8; ++i) *(uint4*)(Bw + i * 64) = v[i];
    }

    // ---- A: direct global from table ----
    const int  slot = (r16 < 8) ? (u4 * 8 + r16) : 32;
    const char* ap  = atbl + (wv * 32) * TPITCH + slot * 16;

    uint4 T0[4], T1[4];
    auto refill = [&](uint4 (&T)[4], int t) {
        const char* p = ap + t * (4 * TPITCH);
        #pragma unroll
        for (int i = 0; i < 4; ++i)
            T[i] = *(const uint4*)(p + i * TPITCH);
    };
    refill(T0, 0);
    refill(T1, 1);

    const __half2 c1 = __floats2half2_rn(-1024.0f, -1024.0f);
    const __half2 c2 = __floats2half2_rn(-7.5f, -7.5f);
    const __half2 cs = __floats2half2_rn(0.0625f, 0.0625f);
    const __half2 cc = __floats2half2_rn(-71.5f, -71.5f);

    floatx4 acc = {0.0f, 0.0f, 0.0f, 0.0f};
    // B word for step s: row r16, word 4s+u4 -> byte r16*BP + s*16 + u4*4
    const char* bp = lds + wv * BWAVE + r16 * BP + u4 * 4;

    auto comp4 = [&](uint4 (&T)[4], int t) {
        #pragma unroll
        for (int i = 0; i < 4; ++i) {
            unsigned w = *(const unsigned*)(bp + (4 * t + i) * 16);
            unsigned w8 = w >> 8;
            V4H8 Bf;
            Bf.u4.x = unpack_even(w,  c1, c2);   // cols +0,+1 (nib 0,4)
            Bf.u4.y = unpack_odd (w,  cs, cc);   // cols +2,+3 (nib 1,5)
            Bf.u4.z = unpack_even(w8, c1, c2);   // cols +4,+5 (nib 2,6)
            Bf.u4.w = unpack_odd (w8, cs, cc);   // cols +6,+7 (nib 3,7)
            V4H8 A;  A.u4 = T[i];
            acc = __builtin_amdgcn_mfma_f32_16x16x32_f16(A.h8, Bf.h8, acc, 0, 0, 0);
        }
    };

    // 8 tiles of 4 steps; A 2 tiles in flight, named buffers (no dyn indexing)
    comp4(T0, 0); refill(T0, 2);
    comp4(T1, 1); refill(T1, 3);
    comp4(T0, 2); refill(T0, 4);
    comp4(T1, 3); refill(T1, 5);
    comp4(T0, 4); refill(T0, 6);
    comp4(T1, 5); refill(T1, 7);
    comp4(T0, 6);
    comp4(T1, 7);

    // ---- cross-wave reduce: C row = 4*u4 + reg (= b), col = r16 ----
    {
        float* red = (float*)(lds + REDOFF) + wv * 128;
        if (u4 < 2) {
            #pragma unroll
            for (int r = 0; r < 4; ++r)
                red[(u4 * 4 + r) * 16 + r16] = acc[r];
        }
    }
    __syncthreads();
    if (tid < 128) {
        const float* rd = (const float*)(lds + REDOFF);
        float sm = 0.0f;
        #pragma unroll
        for (int w = 0; w < NWV; ++w)
            sm += rd[w * 128 + tid];
        out[(tid >> 4) * 8192 + n0 + (tid & 15)] = sm;
    }
}

extern "C" void kernel_launch(void* const* d_in, const int* in_sizes, int n_in,
                              void* d_out, int out_size, void* d_ws, size_t ws_size,
                              hipStream_t stream)
{
    const float* x = (const float*)d_in[0];
    const int*   q = (const int*)d_in[1];
    float* out = (float*)d_out;
    char*  tbl = (char*)d_ws;              // 256*528 = 135168 B

    hipLaunchKernelGGL(build_atable, dim3(256), dim3(64), 0, stream, x, tbl);
    hipLaunchKernelGGL(hi4b_gemm, dim3(512), dim3(512), LDS_BYTES, stream,
                       tbl, q, out);
}